// Round 5
// baseline (800.776 us; speedup 1.0000x reference)
//
#include <hip/hip_runtime.h>
#include <utility>

// SSIM3D fused v5: 2-phase planes (z-conv -> [barrier] -> fused y-conv+ring+SSIM),
// double-buffered zp (1 barrier/plane), 14-plane unroll (compile-time ring slot U
// and buffer parity P), 2016 blocks (~7.9/CU), 19KB LDS.
// Grid: 6 z-tiles x 24 y-tiles x (7 x-chunks * 2 batch).

#define DIMS 192
#define OD   186
#define VOL  (DIMS * DIMS * DIMS)
#define ZCH  32          // z outputs per block (6*32 = 192 covers 186, clipped)
#define NZT  6
#define XCH  27          // x outputs per chunk (7*27 = 189 >= 186)
#define NCHX 7
#define NP   (XCH + 6)   // 33 input planes
#define YT   8
#define YIN  14
#define NBLK (NZT * 24 * NCHX * 2)   // 2016

// zp[buf][f][j][k]: k-pitch 34, f-stride 476, buf-stride 2380. 4760 floats = 19.04 KB.
#define ZP_J 34
#define ZP_F (YIN * ZP_J)   // 476
#define ZP_B (5 * ZP_F)     // 2380
#define LDS_N (2 * ZP_B)

__global__ __launch_bounds__(256, 6)
void ssim3d_kernel(const float* __restrict__ X, const float* __restrict__ Y,
                   double* __restrict__ part, int use_slots) {
    __shared__ float lds[LDS_N];
    __shared__ float wsum[4];
    const int tid = threadIdx.x;

    // 1D Gaussian softmax weights, wave-uniform (SGPR).
    float w[7];
    {
        float s = 0.f;
        #pragma unroll
        for (int t = 0; t < 7; ++t) {
            float d = (float)t - 3.0f;
            w[t] = expf(-d * d / 4.5f);
            s += w[t];
        }
        #pragma unroll
        for (int t = 0; t < 7; ++t)
            w[t] = __uint_as_float(__builtin_amdgcn_readfirstlane(__float_as_uint(w[t] / s)));
    }

    const int z0 = blockIdx.x * ZCH;
    const int y0 = blockIdx.y * YT;
    const int cx = blockIdx.z % NCHX;
    const int n  = blockIdx.z / NCHX;
    const int x0 = cx * XCH;

    const float* Xb = X + (size_t)n * VOL;
    const float* Yb = Y + (size_t)n * VOL;

    // Phase A mapping: thread (zj, zs) -> row zj, z-output pair k = 2zs, 2zs+1
    const int zj = tid >> 4;                 // 0..15, active < 14
    const int zs = tid & 15;
    const bool zact = (zj < YIN);
    const int gy = min(y0 + zj, DIMS - 1);
    const int zbase = z0 + 2 * zs;           // even -> float2-aligned
    const bool ztail = (zbase + 7 > DIMS - 1);   // only last z-tile, zs>=13
    const unsigned rowoff = (unsigned)gy * DIMS + (unsigned)zbase;

    // Phase C mapping: one output point (cj, ck) per thread
    const int cj = tid >> 5;                 // 0..7
    const int ck = tid & 31;                 // 0..31
    const bool cvalid = (z0 + ck < OD) && (y0 + cj < OD);
    const int xmax = DIMS - x0;              // xi < xmax -> output o = x0+xi-6 < 186

    float acc[7][5];
    #pragma unroll
    for (int q = 0; q < 7; ++q)
        #pragma unroll
        for (int m = 0; m < 5; ++m) acc[q][m] = 0.f;

    float lsum = 0.f;
    const float c1 = 1e-4f, c2 = 9e-4f;

    float pfx[8], pfy[8];

    auto loadX = [&](int xi) {
        if (!zact) return;
        int gx = min(x0 + xi, DIMS - 1);
        const float* p = Xb + (size_t)gx * (DIMS * DIMS);
        if (!ztail) {
            const float* q = p + rowoff;
            #pragma unroll
            for (int t = 0; t < 4; ++t) {
                float2 a = *(const float2*)(q + 2 * t);
                pfx[2 * t] = a.x; pfx[2 * t + 1] = a.y;
            }
        } else {
            #pragma unroll
            for (int t = 0; t < 8; ++t)
                pfx[t] = p[(unsigned)gy * DIMS + (unsigned)min(zbase + t, DIMS - 1)];
        }
    };
    auto loadY = [&](int xi) {
        if (!zact) return;
        int gx = min(x0 + xi, DIMS - 1);
        const float* p = Yb + (size_t)gx * (DIMS * DIMS);
        if (!ztail) {
            const float* q = p + rowoff;
            #pragma unroll
            for (int t = 0; t < 4; ++t) {
                float2 a = *(const float2*)(q + 2 * t);
                pfy[2 * t] = a.x; pfy[2 * t + 1] = a.y;
            }
        } else {
            #pragma unroll
            for (int t = 0; t < 8; ++t)
                pfy[t] = p[(unsigned)gy * DIMS + (unsigned)min(zbase + t, DIMS - 1)];
        }
    };

    auto body = [&](int xi, auto uc, auto pc) {
        constexpr int U = decltype(uc)::value;   // xi % 7 (ring rotation)
        constexpr int P = decltype(pc)::value;   // xi % 2 (zp buffer)
        constexpr int BUF = P * ZP_B;

        // ---- Phase A: z-conv (2 outputs x 5 fields) -> zp[P], b64 writes ----
        if (zact) {
            float a0[2] = {0.f, 0.f}, a1[2] = {0.f, 0.f}, a2[2] = {0.f, 0.f},
                  a3[2] = {0.f, 0.f}, a4[2] = {0.f, 0.f};
            #pragma unroll
            for (int t = 0; t < 7; ++t) {
                float wt = w[t];
                #pragma unroll
                for (int o = 0; o < 2; ++o) {
                    float xx = pfx[t + o], yy = pfy[t + o];
                    a0[o] += wt * xx;
                    a1[o] += wt * yy;
                    a2[o] += wt * (xx * xx);
                    a3[o] += wt * (yy * yy);
                    a4[o] += wt * (xx * yy);
                }
            }
            const int wb = BUF + zj * ZP_J + 2 * zs;
            *(float2*)&lds[wb]            = make_float2(a0[0], a0[1]);
            *(float2*)&lds[wb + ZP_F]     = make_float2(a1[0], a1[1]);
            *(float2*)&lds[wb + 2 * ZP_F] = make_float2(a2[0], a2[1]);
            *(float2*)&lds[wb + 3 * ZP_F] = make_float2(a3[0], a3[1]);
            *(float2*)&lds[wb + 4 * ZP_F] = make_float2(a4[0], a4[1]);
        }
        // prefetch next plane (overlaps Phase C after the barrier)
        if (xi + 1 < NP) { loadX(xi + 1); loadY(xi + 1); }
        __syncthreads();

        // ---- Phase C: fused y-conv + ring accumulate + SSIM ----
        const float* src = &lds[BUF + cj * ZP_J + ck];
        float vv[5];
        #pragma unroll
        for (int f = 0; f < 5; ++f) {
            float a = 0.f;
            #pragma unroll
            for (int t = 0; t < 7; ++t) a += w[t] * src[f * ZP_F + t * ZP_J];
            vv[f] = a;
        }
        #pragma unroll
        for (int d = 0; d < 7; ++d) {
            float wq = w[d];
            #pragma unroll
            for (int m = 0; m < 5; ++m)
                acc[(U + 7 - d) % 7][m] += wq * vv[m];   // const indices after unroll
        }
        constexpr int sc = (U + 1) % 7;   // slot completing at this plane (o = xi-6)
        if (xi >= 6 && xi < xmax && cvalid) {
            float mu1 = acc[sc][0], mu2 = acc[sc][1];
            float ex2 = acc[sc][2], ey2 = acc[sc][3], exy = acc[sc][4];
            float mu11 = mu1 * mu1, mu22 = mu2 * mu2, mu12 = mu1 * mu2;
            float num = (2.f * mu12 + c1) * (2.f * (exy - mu12) + c2);
            float den = (mu11 + mu22 + c1) * ((ex2 - mu11) + (ey2 - mu22) + c2);
            lsum += num * __builtin_amdgcn_rcpf(den);
        }
        #pragma unroll
        for (int m = 0; m < 5; ++m) acc[sc][m] = 0.f;
        // No 2nd barrier: next Phase A writes zp[1-P]; zp[P] is rewritten only at
        // xi+2's Phase A, which is behind xi+1's barrier, after all C(xi) reads.
    };

    loadX(0); loadY(0);
#define BODY(i) body(base + (i), std::integral_constant<int, (i) % 7>{}, \
                     std::integral_constant<int, (i) % 2>{})
    #pragma unroll 1
    for (int base = 0; base < 28; base += 14) {
        BODY(0);  BODY(1);  BODY(2);  BODY(3);  BODY(4);  BODY(5);  BODY(6);
        BODY(7);  BODY(8);  BODY(9);  BODY(10); BODY(11); BODY(12); BODY(13);
    }
    {
        const int base = 28;
        BODY(0); BODY(1); BODY(2); BODY(3); BODY(4);
    }
#undef BODY

    // ---- block reduction -> per-block slot (or atomic fallback) ----
    #pragma unroll
    for (int off = 32; off > 0; off >>= 1) lsum += __shfl_down(lsum, off, 64);
    if ((tid & 63) == 0) wsum[tid >> 6] = lsum;
    __syncthreads();
    if (tid == 0) {
        double bs = (double)(wsum[0] + wsum[1] + wsum[2] + wsum[3]);
        if (use_slots) {
            int bid = blockIdx.x + NZT * (blockIdx.y + 24 * blockIdx.z);
            part[bid] = bs;
        } else {
            atomicAdd(part, bs);
        }
    }
}

__global__ void ssim3d_finalize(const double* __restrict__ part, float* __restrict__ out,
                                int use_slots) {
    __shared__ double ws[4];
    const int tid = threadIdx.x;
    if (!use_slots) {
        if (tid == 0) out[0] = (float)(part[0] / 12869712.0);
        return;
    }
    double s = 0.0;
    for (int i = tid; i < NBLK; i += 256) s += part[i];
    #pragma unroll
    for (int off = 32; off > 0; off >>= 1) s += __shfl_down(s, off, 64);
    if ((tid & 63) == 0) ws[tid >> 6] = s;
    __syncthreads();
    if (tid == 0) out[0] = (float)((ws[0] + ws[1] + ws[2] + ws[3]) / 12869712.0);
}

extern "C" void kernel_launch(void* const* d_in, const int* in_sizes, int n_in,
                              void* d_out, int out_size, void* d_ws, size_t ws_size,
                              hipStream_t stream) {
    (void)in_sizes; (void)n_in; (void)out_size;
    const float* x = (const float*)d_in[0];
    const float* y = (const float*)d_in[1];
    float* out = (float*)d_out;
    double* part = (double*)d_ws;
    int use_slots = (ws_size >= NBLK * sizeof(double)) ? 1 : 0;
    if (!use_slots) hipMemsetAsync(d_ws, 0, sizeof(double), stream);
    dim3 grid(NZT, 24, NCHX * 2);
    ssim3d_kernel<<<grid, 256, 0, stream>>>(x, y, part, use_slots);
    ssim3d_finalize<<<1, 256, 0, stream>>>(part, out, use_slots);
}

// Round 6
// 431.742 us; speedup vs baseline: 1.8548x; 1.8548x over previous
//
#include <hip/hip_runtime.h>
#include <utility>

// SSIM3D fused v6 = v5 structure with the spill fixed.
// v5 post-mortem: __launch_bounds__(256,6) capped regs at ~80 -> compiler spilled
// acc ring + prefetch regs to scratch (WRITE_SIZE 1.2GB, VALUBusy 10%). This version
// uses (256,4): 128-reg budget, everything stays in VGPR/AGPR.
// Structure: 2-phase planes (z-conv -> barrier -> fused y-conv+ring+SSIM),
// double-buffered zp (1 barrier/plane), 14-plane unroll (compile-time ring slot U,
// buffer parity P), grid 6x24x14 = 2016 blocks, 19KB LDS, conflict-free layouts.

#define DIMS 192
#define OD   186
#define VOL  (DIMS * DIMS * DIMS)
#define ZCH  32          // z outputs per block (6*32 = 192 covers 186, clipped)
#define NZT  6
#define XCH  27          // x outputs per chunk (7*27 = 189 >= 186)
#define NCHX 7
#define NP   (XCH + 6)   // 33 input planes
#define YT   8
#define YIN  14
#define NBLK (NZT * 24 * NCHX * 2)   // 2016

// zp[buf][f][j][k]: k-pitch 34, f-stride 476, buf-stride 2380. 4760 floats = 19.04 KB.
#define ZP_J 34
#define ZP_F (YIN * ZP_J)   // 476
#define ZP_B (5 * ZP_F)     // 2380
#define LDS_N (2 * ZP_B)

__global__ __launch_bounds__(256, 4)
void ssim3d_kernel(const float* __restrict__ X, const float* __restrict__ Y,
                   double* __restrict__ part, int use_slots) {
    __shared__ float lds[LDS_N];
    __shared__ float wsum[4];
    const int tid = threadIdx.x;

    // 1D Gaussian softmax weights, wave-uniform (SGPR).
    float w[7];
    {
        float s = 0.f;
        #pragma unroll
        for (int t = 0; t < 7; ++t) {
            float d = (float)t - 3.0f;
            w[t] = expf(-d * d / 4.5f);
            s += w[t];
        }
        #pragma unroll
        for (int t = 0; t < 7; ++t)
            w[t] = __uint_as_float(__builtin_amdgcn_readfirstlane(__float_as_uint(w[t] / s)));
    }

    const int z0 = blockIdx.x * ZCH;
    const int y0 = blockIdx.y * YT;
    const int cx = blockIdx.z % NCHX;
    const int n  = blockIdx.z / NCHX;
    const int x0 = cx * XCH;

    const float* Xb = X + (size_t)n * VOL;
    const float* Yb = Y + (size_t)n * VOL;

    // Phase A mapping: thread (zj, zs) -> row zj, z-output pair k = 2zs, 2zs+1
    const int zj = tid >> 4;                 // 0..15, active < 14
    const int zs = tid & 15;
    const bool zact = (zj < YIN);
    const int gy = min(y0 + zj, DIMS - 1);
    const int zbase = z0 + 2 * zs;           // even -> float2-aligned
    const bool ztail = (zbase + 7 > DIMS - 1);   // only last z-tile, zs>=13
    const unsigned rowoff = (unsigned)gy * DIMS + (unsigned)zbase;

    // Phase C mapping: one output point (cj, ck) per thread
    const int cj = tid >> 5;                 // 0..7
    const int ck = tid & 31;                 // 0..31
    const bool cvalid = (z0 + ck < OD) && (y0 + cj < OD);
    const int xmax = DIMS - x0;              // xi < xmax -> output o = x0+xi-6 < 186

    float acc[7][5];
    #pragma unroll
    for (int q = 0; q < 7; ++q)
        #pragma unroll
        for (int m = 0; m < 5; ++m) acc[q][m] = 0.f;

    float lsum = 0.f;
    const float c1 = 1e-4f, c2 = 9e-4f;

    float pfx[8], pfy[8];

    auto loadX = [&](int xi) {
        if (!zact) return;
        int gx = min(x0 + xi, DIMS - 1);
        const float* p = Xb + (size_t)gx * (DIMS * DIMS);
        if (!ztail) {
            const float* q = p + rowoff;
            #pragma unroll
            for (int t = 0; t < 4; ++t) {
                float2 a = *(const float2*)(q + 2 * t);
                pfx[2 * t] = a.x; pfx[2 * t + 1] = a.y;
            }
        } else {
            const float* q = p + (unsigned)gy * DIMS;
            #pragma unroll
            for (int t = 0; t < 8; ++t)
                pfx[t] = q[(unsigned)min(zbase + t, DIMS - 1)];
        }
    };
    auto loadY = [&](int xi) {
        if (!zact) return;
        int gx = min(x0 + xi, DIMS - 1);
        const float* p = Yb + (size_t)gx * (DIMS * DIMS);
        if (!ztail) {
            const float* q = p + rowoff;
            #pragma unroll
            for (int t = 0; t < 4; ++t) {
                float2 a = *(const float2*)(q + 2 * t);
                pfy[2 * t] = a.x; pfy[2 * t + 1] = a.y;
            }
        } else {
            const float* q = p + (unsigned)gy * DIMS;
            #pragma unroll
            for (int t = 0; t < 8; ++t)
                pfy[t] = q[(unsigned)min(zbase + t, DIMS - 1)];
        }
    };

    auto body = [&](int xi, auto uc, auto pc) {
        constexpr int U = decltype(uc)::value;   // xi % 7 (ring rotation)
        constexpr int P = decltype(pc)::value;   // xi % 2 (zp buffer)
        constexpr int BUF = P * ZP_B;

        // ---- Phase A: z-conv (2 outputs x 5 fields) -> zp[P], b64 writes ----
        if (zact) {
            float a0[2] = {0.f, 0.f}, a1[2] = {0.f, 0.f}, a2[2] = {0.f, 0.f},
                  a3[2] = {0.f, 0.f}, a4[2] = {0.f, 0.f};
            #pragma unroll
            for (int t = 0; t < 7; ++t) {
                float wt = w[t];
                #pragma unroll
                for (int o = 0; o < 2; ++o) {
                    float xx = pfx[t + o], yy = pfy[t + o];
                    a0[o] += wt * xx;
                    a1[o] += wt * yy;
                    a2[o] += wt * (xx * xx);
                    a3[o] += wt * (yy * yy);
                    a4[o] += wt * (xx * yy);
                }
            }
            const int wb = BUF + zj * ZP_J + 2 * zs;
            *(float2*)&lds[wb]            = make_float2(a0[0], a0[1]);
            *(float2*)&lds[wb + ZP_F]     = make_float2(a1[0], a1[1]);
            *(float2*)&lds[wb + 2 * ZP_F] = make_float2(a2[0], a2[1]);
            *(float2*)&lds[wb + 3 * ZP_F] = make_float2(a3[0], a3[1]);
            *(float2*)&lds[wb + 4 * ZP_F] = make_float2(a4[0], a4[1]);
        }
        // prefetch next plane (overlaps Phase C after the barrier)
        if (xi + 1 < NP) { loadX(xi + 1); loadY(xi + 1); }
        __syncthreads();

        // ---- Phase C: fused y-conv + ring accumulate + SSIM ----
        const float* src = &lds[BUF + cj * ZP_J + ck];
        float vv[5];
        #pragma unroll
        for (int f = 0; f < 5; ++f) {
            float a = 0.f;
            #pragma unroll
            for (int t = 0; t < 7; ++t) a += w[t] * src[f * ZP_F + t * ZP_J];
            vv[f] = a;
        }
        #pragma unroll
        for (int d = 0; d < 7; ++d) {
            float wq = w[d];
            #pragma unroll
            for (int m = 0; m < 5; ++m)
                acc[(U + 7 - d) % 7][m] += wq * vv[m];   // const indices after unroll
        }
        constexpr int sc = (U + 1) % 7;   // slot completing at this plane (o = xi-6)
        if (xi >= 6 && xi < xmax && cvalid) {
            float mu1 = acc[sc][0], mu2 = acc[sc][1];
            float ex2 = acc[sc][2], ey2 = acc[sc][3], exy = acc[sc][4];
            float mu11 = mu1 * mu1, mu22 = mu2 * mu2, mu12 = mu1 * mu2;
            float num = (2.f * mu12 + c1) * (2.f * (exy - mu12) + c2);
            float den = (mu11 + mu22 + c1) * ((ex2 - mu11) + (ey2 - mu22) + c2);
            lsum += num * __builtin_amdgcn_rcpf(den);
        }
        #pragma unroll
        for (int m = 0; m < 5; ++m) acc[sc][m] = 0.f;
        // No 2nd barrier: next Phase A writes zp[1-P]; zp[P] is rewritten only at
        // xi+2's Phase A, which is behind xi+1's barrier, after all C(xi) reads.
    };

    loadX(0); loadY(0);
#define BODY(i) body(base + (i), std::integral_constant<int, (i) % 7>{}, \
                     std::integral_constant<int, (i) % 2>{})
    #pragma unroll 1
    for (int base = 0; base < 28; base += 14) {
        BODY(0);  BODY(1);  BODY(2);  BODY(3);  BODY(4);  BODY(5);  BODY(6);
        BODY(7);  BODY(8);  BODY(9);  BODY(10); BODY(11); BODY(12); BODY(13);
    }
    {
        const int base = 28;
        BODY(0); BODY(1); BODY(2); BODY(3); BODY(4);
    }
#undef BODY

    // ---- block reduction -> per-block slot (or atomic fallback) ----
    #pragma unroll
    for (int off = 32; off > 0; off >>= 1) lsum += __shfl_down(lsum, off, 64);
    if ((tid & 63) == 0) wsum[tid >> 6] = lsum;
    __syncthreads();
    if (tid == 0) {
        double bs = (double)(wsum[0] + wsum[1] + wsum[2] + wsum[3]);
        if (use_slots) {
            int bid = blockIdx.x + NZT * (blockIdx.y + 24 * blockIdx.z);
            part[bid] = bs;
        } else {
            atomicAdd(part, bs);
        }
    }
}

__global__ void ssim3d_finalize(const double* __restrict__ part, float* __restrict__ out,
                                int use_slots) {
    __shared__ double ws[4];
    const int tid = threadIdx.x;
    if (!use_slots) {
        if (tid == 0) out[0] = (float)(part[0] / 12869712.0);
        return;
    }
    double s = 0.0;
    for (int i = tid; i < NBLK; i += 256) s += part[i];
    #pragma unroll
    for (int off = 32; off > 0; off >>= 1) s += __shfl_down(s, off, 64);
    if ((tid & 63) == 0) ws[tid >> 6] = s;
    __syncthreads();
    if (tid == 0) out[0] = (float)((ws[0] + ws[1] + ws[2] + ws[3]) / 12869712.0);
}

extern "C" void kernel_launch(void* const* d_in, const int* in_sizes, int n_in,
                              void* d_out, int out_size, void* d_ws, size_t ws_size,
                              hipStream_t stream) {
    (void)in_sizes; (void)n_in; (void)out_size;
    const float* x = (const float*)d_in[0];
    const float* y = (const float*)d_in[1];
    float* out = (float*)d_out;
    double* part = (double*)d_ws;
    int use_slots = (ws_size >= NBLK * sizeof(double)) ? 1 : 0;
    if (!use_slots) hipMemsetAsync(d_ws, 0, sizeof(double), stream);
    dim3 grid(NZT, 24, NCHX * 2);
    ssim3d_kernel<<<grid, 256, 0, stream>>>(x, y, part, use_slots);
    ssim3d_finalize<<<1, 256, 0, stream>>>(part, out, use_slots);
}

// Round 7
// 241.932 us; speedup vs baseline: 3.3099x; 1.7846x over previous
//
#include <hip/hip_runtime.h>
#include <utility>

// SSIM3D fused v7 = v6 phases with the register allocator tamed.
// v6 post-mortem: __launch_bounds__(256,4) is only a MIN waves/EU -> allocator
// still targeted 8 waves/SIMD (64-VGPR step) and spilled the acc ring
// (WRITE_SIZE 118MB of scratch, VALUBusy 21.6%, 14-body unroll ~45KB thrashed I$).
// Fixes: (1) amdgpu_waves_per_eu(4,4) pins budget at 128 VGPRs -> no spill;
// (2) dynamic ring shift -> unroll 2 only (small, I$-resident body);
// (3) last z-tile shifted to z0=154 (+kmin=6 dedup) -> no ztail divergence,
//     all loads aligned float2.
// Structure: per plane: Phase A z-conv (reg window) -> zp[P]; prefetch xi+1;
// barrier; Phase C fused y-conv + ring accumulate + SSIM. 1 barrier/plane.
// Grid 6x24x14 = 2016 blocks, LDS 19.1KB.

#define DIMS 192
#define OD   186
#define VOL  (DIMS * DIMS * DIMS)
#define ZCH  32          // z outputs per block
#define NZT  6           // tiles at z0 = 0,32,64,96,128,154 (last shifted, kmin=6)
#define XCH  27          // x outputs per chunk (7*27 = 189 >= 186)
#define NCHX 7
#define NP   (XCH + 6)   // 33 input planes
#define YT   8
#define YIN  14
#define NBLK (NZT * 24 * NCHX * 2)   // 2016

// zp[buf][f][j][k]: k-pitch 34, f-stride 476, buf-stride 2380. 4760 floats = 19.04 KB.
#define ZP_J 34
#define ZP_F (YIN * ZP_J)   // 476
#define ZP_B (5 * ZP_F)     // 2380
#define LDS_N (2 * ZP_B)

__global__ __launch_bounds__(256) __attribute__((amdgpu_waves_per_eu(4, 4)))
void ssim3d_kernel(const float* __restrict__ X, const float* __restrict__ Y,
                   double* __restrict__ part, int use_slots) {
    __shared__ float lds[LDS_N];
    __shared__ float wsum[4];
    const int tid = threadIdx.x;

    // 1D Gaussian softmax weights, wave-uniform (SGPR).
    float w[7];
    {
        float s = 0.f;
        #pragma unroll
        for (int t = 0; t < 7; ++t) {
            float d = (float)t - 3.0f;
            w[t] = expf(-d * d / 4.5f);
            s += w[t];
        }
        #pragma unroll
        for (int t = 0; t < 7; ++t)
            w[t] = __uint_as_float(__builtin_amdgcn_readfirstlane(__float_as_uint(w[t] / s)));
    }

    const int bz = blockIdx.x;
    const int z0 = (bz == NZT - 1) ? 154 : bz * ZCH;   // last tile shifted: window ends at 191
    const int kmin = (bz == NZT - 1) ? 6 : 0;          // dedup overlap with tile 4
    const int y0 = blockIdx.y * YT;
    const int cx = blockIdx.z % NCHX;
    const int n  = blockIdx.z / NCHX;
    const int x0 = cx * XCH;

    const float* Xb = X + (size_t)n * VOL;
    const float* Yb = Y + (size_t)n * VOL;

    // Phase A mapping: thread (zj, zs) -> row zj, z-output pair k = 2zs, 2zs+1.
    // Window = floats zbase..zbase+7, always in-bounds (z0 <= 154 -> max 191).
    const int zj = tid >> 4;                 // 0..15, active < 14
    const int zs = tid & 15;
    const bool zact = (zj < YIN);
    const int gy = min(y0 + zj, DIMS - 1);
    const unsigned rowoff = (unsigned)gy * DIMS + (unsigned)(z0 + 2 * zs);

    // Phase C mapping: one output point (cj, ck) per thread
    const int cj = tid >> 5;                 // 0..7
    const int ck = tid & 31;                 // 0..31
    const bool cvalid = (y0 + cj < OD) && (ck >= kmin);
    const int xmax = DIMS - x0;              // xi < xmax -> output o = x0+xi-6 < 186

    float acc[7][5];
    #pragma unroll
    for (int q = 0; q < 7; ++q)
        #pragma unroll
        for (int m = 0; m < 5; ++m) acc[q][m] = 0.f;

    float lsum = 0.f;
    const float c1 = 1e-4f, c2 = 9e-4f;

    float pfx[8], pfy[8];

    auto loadPF = [&](int xi) {
        if (!zact) return;
        int gx = min(x0 + xi, DIMS - 1);     // uniform (SGPR) clamp
        const float* qx = Xb + (size_t)gx * (DIMS * DIMS) + rowoff;
        const float* qy = Yb + (size_t)gx * (DIMS * DIMS) + rowoff;
        #pragma unroll
        for (int t = 0; t < 4; ++t) {
            float2 a = *(const float2*)(qx + 2 * t);
            pfx[2 * t] = a.x; pfx[2 * t + 1] = a.y;
        }
        #pragma unroll
        for (int t = 0; t < 4; ++t) {
            float2 a = *(const float2*)(qy + 2 * t);
            pfy[2 * t] = a.x; pfy[2 * t + 1] = a.y;
        }
    };

    auto body = [&](int xi, auto pc) {
        constexpr int P = decltype(pc)::value;   // xi % 2 (zp buffer)
        constexpr int BUF = P * ZP_B;

        // ---- Phase A: z-conv (2 outputs x 5 fields) -> zp[P], b64 writes ----
        if (zact) {
            float a0[2] = {0.f, 0.f}, a1[2] = {0.f, 0.f}, a2[2] = {0.f, 0.f},
                  a3[2] = {0.f, 0.f}, a4[2] = {0.f, 0.f};
            #pragma unroll
            for (int t = 0; t < 7; ++t) {
                float wt = w[t];
                #pragma unroll
                for (int o = 0; o < 2; ++o) {
                    float xx = pfx[t + o], yy = pfy[t + o];
                    a0[o] += wt * xx;
                    a1[o] += wt * yy;
                    a2[o] += wt * (xx * xx);
                    a3[o] += wt * (yy * yy);
                    a4[o] += wt * (xx * yy);
                }
            }
            const int wb = BUF + zj * ZP_J + 2 * zs;
            *(float2*)&lds[wb]            = make_float2(a0[0], a0[1]);
            *(float2*)&lds[wb + ZP_F]     = make_float2(a1[0], a1[1]);
            *(float2*)&lds[wb + 2 * ZP_F] = make_float2(a2[0], a2[1]);
            *(float2*)&lds[wb + 3 * ZP_F] = make_float2(a3[0], a3[1]);
            *(float2*)&lds[wb + 4 * ZP_F] = make_float2(a4[0], a4[1]);
        }
        // prefetch next plane (pf consumed above; in-order issue makes WAR safe)
        if (xi + 1 < NP) loadPF(xi + 1);
        __syncthreads();

        // ---- Phase C: fused y-conv + ring accumulate + SSIM ----
        const float* src = &lds[BUF + cj * ZP_J + ck];
        float vv[5];
        #pragma unroll
        for (int f = 0; f < 5; ++f) {
            float a = 0.f;
            #pragma unroll
            for (int t = 0; t < 7; ++t) a += w[t] * src[f * ZP_F + t * ZP_J];
            vv[f] = a;
        }
        #pragma unroll
        for (int q = 0; q < 7; ++q) {
            float wq = w[6 - q];
            #pragma unroll
            for (int m = 0; m < 5; ++m) acc[q][m] += wq * vv[m];
        }
        if (xi >= 6 && xi < xmax && cvalid) {
            float mu1 = acc[0][0], mu2 = acc[0][1];
            float ex2 = acc[0][2], ey2 = acc[0][3], exy = acc[0][4];
            float mu11 = mu1 * mu1, mu22 = mu2 * mu2, mu12 = mu1 * mu2;
            float num = (2.f * mu12 + c1) * (2.f * (exy - mu12) + c2);
            float den = (mu11 + mu22 + c1) * ((ex2 - mu11) + (ey2 - mu22) + c2);
            lsum += num * __builtin_amdgcn_rcpf(den);
        }
        // shift ring (constant indices -> register moves)
        #pragma unroll
        for (int q = 0; q < 6; ++q)
            #pragma unroll
            for (int m = 0; m < 5; ++m) acc[q][m] = acc[q + 1][m];
        #pragma unroll
        for (int m = 0; m < 5; ++m) acc[6][m] = 0.f;
        // No 2nd barrier: next Phase A writes zp[1-P]; zp[P] is rewritten only at
        // xi+2's Phase A, which is behind xi+1's barrier, after all C(xi) reads.
    };

    loadPF(0);
    #pragma unroll 1
    for (int xi = 0; xi < NP - 1; xi += 2) {
        body(xi,     std::integral_constant<int, 0>{});
        body(xi + 1, std::integral_constant<int, 1>{});
    }
    body(NP - 1, std::integral_constant<int, 0>{});   // NP-1 = 32, even

    // ---- block reduction -> per-block slot (or atomic fallback) ----
    #pragma unroll
    for (int off = 32; off > 0; off >>= 1) lsum += __shfl_down(lsum, off, 64);
    if ((tid & 63) == 0) wsum[tid >> 6] = lsum;
    __syncthreads();
    if (tid == 0) {
        double bs = (double)(wsum[0] + wsum[1] + wsum[2] + wsum[3]);
        if (use_slots) {
            int bid = blockIdx.x + NZT * (blockIdx.y + 24 * blockIdx.z);
            part[bid] = bs;
        } else {
            atomicAdd(part, bs);
        }
    }
}

__global__ void ssim3d_finalize(const double* __restrict__ part, float* __restrict__ out,
                                int use_slots) {
    __shared__ double ws[4];
    const int tid = threadIdx.x;
    if (!use_slots) {
        if (tid == 0) out[0] = (float)(part[0] / 12869712.0);
        return;
    }
    double s = 0.0;
    for (int i = tid; i < NBLK; i += 256) s += part[i];
    #pragma unroll
    for (int off = 32; off > 0; off >>= 1) s += __shfl_down(s, off, 64);
    if ((tid & 63) == 0) ws[tid >> 6] = s;
    __syncthreads();
    if (tid == 0) out[0] = (float)((ws[0] + ws[1] + ws[2] + ws[3]) / 12869712.0);
}

extern "C" void kernel_launch(void* const* d_in, const int* in_sizes, int n_in,
                              void* d_out, int out_size, void* d_ws, size_t ws_size,
                              hipStream_t stream) {
    (void)in_sizes; (void)n_in; (void)out_size;
    const float* x = (const float*)d_in[0];
    const float* y = (const float*)d_in[1];
    float* out = (float*)d_out;
    double* part = (double*)d_ws;
    int use_slots = (ws_size >= NBLK * sizeof(double)) ? 1 : 0;
    if (!use_slots) hipMemsetAsync(d_ws, 0, sizeof(double), stream);
    dim3 grid(NZT, 24, NCHX * 2);
    ssim3d_kernel<<<grid, 256, 0, stream>>>(x, y, part, use_slots);
    ssim3d_finalize<<<1, 256, 0, stream>>>(part, out, use_slots);
}